// Round 1
// baseline (515.059 us; speedup 1.0000x reference)
//
#include <hip/hip_runtime.h>

#define TPB 256
#define NB  2048   // grid-stride blocks; partial sums = 8 KB in d_ws

// Stage rows (float4) -> normalize -> LDS (SoA) -> per-batch Gram loss -> block partial
__global__ __launch_bounds__(TPB, 4) void reg_loss_k1(
    const float4* __restrict__ in, float* __restrict__ partial, int B)
{
    __shared__ float lx[6 * TPB];
    __shared__ float ly[6 * TPB];
    __shared__ float lz[6 * TPB];
    __shared__ float wsum[TPB / 64];

    const int t = threadIdx.x;
    const long long nrows = (long long)B * 6;
    float acc = 0.f;

    const int ntiles = (B + TPB - 1) / TPB;
    for (int tile = blockIdx.x; tile < ntiles; tile += gridDim.x) {
        const long long rowbase = (long long)tile * (TPB * 6);

        // ---- staging: 1536 consecutive float4 loads, fully coalesced ----
        #pragma unroll
        for (int j = 0; j < 6; ++j) {
            const int r = j * TPB + t;
            const long long g = rowbase + r;
            float x = 0.f, y = 0.f, z = 0.f;
            if (g < nrows) {
                float4 q = in[g];          // q.x is the dropped column 0
                x = q.y; y = q.z; z = q.w;
                float inv = rsqrtf(x * x + y * y + z * z);
                x *= inv; y *= inv; z *= inv;
            }
            lx[r] = x; ly[r] = y; lz[r] = z;
        }
        __syncthreads();

        // ---- per-batch Gram loss ----
        const int b = tile * TPB + t;
        if (b < B) {
            const int rb = t * 6;
            float loss = 0.f;
            #pragma unroll
            for (int k = 0; k < 2; ++k) {
                const int o = rb + 3 * k;
                const float x0 = lx[o],     y0 = ly[o],     z0 = lz[o];
                const float x1 = lx[o + 1], y1 = ly[o + 1], z1 = lz[o + 1];
                const float x2 = lx[o + 2], y2 = ly[o + 2], z2 = lz[o + 2];
                const float d00 = x0 * x0 + y0 * y0 + z0 * z0 - 1.f;
                const float d11 = x1 * x1 + y1 * y1 + z1 * z1 - 1.f;
                const float d22 = x2 * x2 + y2 * y2 + z2 * z2 - 1.f;
                const float d01 = x0 * x1 + y0 * y1 + z0 * z1;
                const float d02 = x0 * x2 + y0 * y2 + z0 * z2;
                const float d12 = x1 * x2 + y1 * y2 + z1 * z2;
                loss += d00 * d00 + d11 * d11 + d22 * d22
                      + 2.f * (d01 * d01 + d02 * d02 + d12 * d12);
            }
            acc += loss;
        }
        __syncthreads();   // before next tile overwrites LDS
    }

    // ---- wave reduce (64 lanes) ----
    for (int off = 32; off > 0; off >>= 1)
        acc += __shfl_down(acc, off, 64);
    if ((t & 63) == 0) wsum[t >> 6] = acc;
    __syncthreads();
    if (t == 0) {
        float s = 0.f;
        #pragma unroll
        for (int w = 0; w < TPB / 64; ++w) s += wsum[w];
        partial[blockIdx.x] = s;
    }
}

// Reduce NB partials -> mean, in double for safety (single block).
__global__ __launch_bounds__(TPB) void reg_loss_k2(
    const float* __restrict__ partial, float* __restrict__ out, int n, int B)
{
    __shared__ double wsum[TPB / 64];
    const int t = threadIdx.x;
    double s = 0.0;
    for (int i = t; i < n; i += TPB) s += (double)partial[i];
    for (int off = 32; off > 0; off >>= 1)
        s += __shfl_down(s, off, 64);
    if ((t & 63) == 0) wsum[t >> 6] = s;
    __syncthreads();
    if (t == 0) {
        double tot = 0.0;
        #pragma unroll
        for (int w = 0; w < TPB / 64; ++w) tot += wsum[w];
        out[0] = (float)(tot / (double)B);
    }
}

extern "C" void kernel_launch(void* const* d_in, const int* in_sizes, int n_in,
                              void* d_out, int out_size, void* d_ws, size_t ws_size,
                              hipStream_t stream) {
    const float4* in = (const float4*)d_in[0];
    const int B = in_sizes[0] / 24;            // (B, 6, 4) fp32
    float* partial = (float*)d_ws;

    int nb = NB;
    if ((size_t)nb * sizeof(float) > ws_size)  // defensive: shrink if scratch is tiny
        nb = (int)(ws_size / sizeof(float));
    if (nb < 1) nb = 1;

    reg_loss_k1<<<nb, TPB, 0, stream>>>(in, partial, B);
    reg_loss_k2<<<1, TPB, 0, stream>>>(partial, (float*)d_out, nb, B);
}

// Round 2
// 514.985 us; speedup vs baseline: 1.0001x; 1.0001x over previous
//
#include <hip/hip_runtime.h>

#define TPB 256
#define NB  4096   // 4096 blocks x 256 thr = 1,048,576 threads; 4 batches/thread at B=4.19e6

__device__ __forceinline__ float group_loss(const float4& a, const float4& b, const float4& c) {
    // vectors are (y,z,w) of each float4 (column 0 dropped)
    const float n0 = a.y * a.y + a.z * a.z + a.w * a.w;
    const float n1 = b.y * b.y + b.z * b.z + b.w * b.w;
    const float n2 = c.y * c.y + c.z * c.z + c.w * c.w;
    const float p01 = a.y * b.y + a.z * b.z + a.w * b.w;
    const float p02 = a.y * c.y + a.z * c.z + a.w * c.w;
    const float p12 = b.y * c.y + b.z * c.z + b.w * c.w;
    const float r0 = rsqrtf(n0), r1 = rsqrtf(n1), r2 = rsqrtf(n2);
    const float d01 = p01 * r0 * r1;
    const float d02 = p02 * r0 * r2;
    const float d12 = p12 * r1 * r2;
    // diagonal terms <u_i,u_i> - 1 are exactly 0 in exact arithmetic; fp32 residual
    // in the reference contributes ~1e-14 to the mean — far below threshold. Skip.
    return 2.f * (d01 * d01 + d02 * d02 + d12 * d12);
}

__global__ __launch_bounds__(TPB) void reg_loss_k1(
    const float4* __restrict__ in, float* __restrict__ partial, int B)
{
    __shared__ float wsum[TPB / 64];
    const int t = threadIdx.x;
    const int stride = gridDim.x * TPB;
    float acc = 0.f;

    for (int b = blockIdx.x * TPB + t; b < B; b += stride) {
        const float4* p = in + (size_t)b * 6;
        const float4 q0 = p[0];
        const float4 q1 = p[1];
        const float4 q2 = p[2];
        const float4 q3 = p[3];
        const float4 q4 = p[4];
        const float4 q5 = p[5];
        acc += group_loss(q0, q1, q2);
        acc += group_loss(q3, q4, q5);
    }

    // wave (64-lane) reduce
    for (int off = 32; off > 0; off >>= 1)
        acc += __shfl_down(acc, off, 64);
    if ((t & 63) == 0) wsum[t >> 6] = acc;
    __syncthreads();
    if (t == 0) {
        float s = 0.f;
        #pragma unroll
        for (int w = 0; w < TPB / 64; ++w) s += wsum[w];
        partial[blockIdx.x] = s;
    }
}

// Reduce partials -> mean (double accumulation, single block).
__global__ __launch_bounds__(TPB) void reg_loss_k2(
    const float* __restrict__ partial, float* __restrict__ out, int n, int B)
{
    __shared__ double wsum[TPB / 64];
    const int t = threadIdx.x;
    double s = 0.0;
    for (int i = t; i < n; i += TPB) s += (double)partial[i];
    for (int off = 32; off > 0; off >>= 1)
        s += __shfl_down(s, off, 64);
    if ((t & 63) == 0) wsum[t >> 6] = s;
    __syncthreads();
    if (t == 0) {
        double tot = 0.0;
        #pragma unroll
        for (int w = 0; w < TPB / 64; ++w) tot += wsum[w];
        out[0] = (float)(tot / (double)B);
    }
}

extern "C" void kernel_launch(void* const* d_in, const int* in_sizes, int n_in,
                              void* d_out, int out_size, void* d_ws, size_t ws_size,
                              hipStream_t stream) {
    const float4* in = (const float4*)d_in[0];
    const int B = in_sizes[0] / 24;            // (B, 6, 4) fp32
    float* partial = (float*)d_ws;

    int nb = NB;
    if ((size_t)nb * sizeof(float) > ws_size)
        nb = (int)(ws_size / sizeof(float));
    if (nb < 1) nb = 1;

    reg_loss_k1<<<nb, TPB, 0, stream>>>(in, partial, B);
    reg_loss_k2<<<1, TPB, 0, stream>>>(partial, (float*)d_out, nb, B);
}